// Round 3
// baseline (218.350 us; speedup 1.0000x reference)
//
#include <hip/hip_runtime.h>
#include <math.h>

// B=2, C=O=256, H=W=64, K=33 offsets (D=4 rings).
typedef __attribute__((ext_vector_type(4))) float f4;

__device__ __forceinline__ int iclamp(int x, int lo, int hi) { return min(max(x, lo), hi); }

// k=0:(0,0); rings s=1..4: (-s,-s),(-s,0),(-s,s),(0,-s),(0,s),(s,-s),(s,0),(s,s)
#define DX_TBL {0, -1,-1,-1,0,0,1,1,1, -2,-2,-2,0,0,2,2,2, -3,-3,-3,0,0,3,3,3, -4,-4,-4,0,0,4,4,4}
#define DY_TBL {0, -1,0,1,-1,1,-1,0,1, -2,0,2,-2,2,-2,0,2, -3,0,3,-3,3,-3,0,3, -4,0,4,-4,4,-4,0,4}

// ---------------------------------------------------------------------------
// GEMM: E[b][o][p] = sum_c W[o][c] * X[b][c][p] + bias[o]
// M=256(o), N=4096(p), K=256(c). Tile 64o x 64p, K-chunk 32, reg double-buffer,
// ONE barrier per chunk (global load of chunk i+1 overlaps compute of chunk i).
// ---------------------------------------------------------------------------
__global__ __launch_bounds__(256) void gemm_f32(
    const float* __restrict__ Wf, const float* __restrict__ bf,
    const float* __restrict__ Wg, const float* __restrict__ bg,
    const float* __restrict__ Ft, const float* __restrict__ FtE,
    float* __restrict__ Ef, float* __restrict__ Eg)
{
    __shared__ float As[2][32][68];   // [c][o] transposed; pad 68 -> <=4-way on writes, reads broadcast
    __shared__ float Bs[2][32][64];   // [c][p]; b128 reads 2-way (free)

    const int bn = blockIdx.x, bm = blockIdx.y, gb = blockIdx.z;
    const int g = gb >> 1, b = gb & 1;
    const float* Wmat = g ? Wg : Wf;
    const float* bias = g ? bg : bf;
    const float* X = (g ? FtE : Ft) + (size_t)b * 256 * 4096;
    float* E = (g ? Eg : Ef) + (size_t)b * 256 * 4096;

    const int tid = threadIdx.x;
    const int tn = tid & 15, tm = tid >> 4;       // tn -> p quad, tm -> o quad
    const int m0 = bm * 64, n0 = bn * 64;
    const int fa0 = tid, fa1 = tid + 256;         // f4 staging ids (512 f4 per tile)

    float acc[4][4] = {};
    f4 av[2], bv[2];

    // prologue: stage chunk 0
    {
        av[0] = *(const f4*)&Wmat[(m0 + (fa0 >> 3)) * 256 + (fa0 & 7) * 4];
        av[1] = *(const f4*)&Wmat[(m0 + (fa1 >> 3)) * 256 + (fa1 & 7) * 4];
        bv[0] = *(const f4*)&X[((fa0 >> 4)) * 4096 + n0 + (fa0 & 15) * 4];
        bv[1] = *(const f4*)&X[((fa1 >> 4)) * 4096 + n0 + (fa1 & 15) * 4];
        #pragma unroll
        for (int j = 0; j < 2; ++j) {
            int f = j ? fa1 : fa0;
            int o = f >> 3, cq = f & 7;
            f4 v = j ? av[1] : av[0];
            As[0][cq * 4 + 0][o] = v.x; As[0][cq * 4 + 1][o] = v.y;
            As[0][cq * 4 + 2][o] = v.z; As[0][cq * 4 + 3][o] = v.w;
            int c = f >> 4, p4 = f & 15;
            *(f4*)&Bs[0][c][p4 * 4] = j ? bv[1] : bv[0];
        }
    }
    __syncthreads();

    for (int ch = 0; ch < 8; ++ch) {
        const int buf = ch & 1;
        if (ch < 7) {
            const int kk = (ch + 1) * 32;
            av[0] = *(const f4*)&Wmat[(m0 + (fa0 >> 3)) * 256 + kk + (fa0 & 7) * 4];
            av[1] = *(const f4*)&Wmat[(m0 + (fa1 >> 3)) * 256 + kk + (fa1 & 7) * 4];
            bv[0] = *(const f4*)&X[(kk + (fa0 >> 4)) * 4096 + n0 + (fa0 & 15) * 4];
            bv[1] = *(const f4*)&X[(kk + (fa1 >> 4)) * 4096 + n0 + (fa1 & 15) * 4];
        }
        #pragma unroll 8
        for (int k = 0; k < 32; ++k) {
            f4 a = *(const f4*)&As[buf][k][tm * 4];   // broadcast across tn
            f4 bb = *(const f4*)&Bs[buf][k][tn * 4];
            #pragma unroll
            for (int ii = 0; ii < 4; ++ii)
                #pragma unroll
                for (int jj = 0; jj < 4; ++jj)
                    acc[ii][jj] += a[ii] * bb[jj];
        }
        if (ch < 7) {
            const int nb = buf ^ 1;
            #pragma unroll
            for (int j = 0; j < 2; ++j) {
                int f = j ? fa1 : fa0;
                int o = f >> 3, cq = f & 7;
                f4 v = j ? av[1] : av[0];
                As[nb][cq * 4 + 0][o] = v.x; As[nb][cq * 4 + 1][o] = v.y;
                As[nb][cq * 4 + 2][o] = v.z; As[nb][cq * 4 + 3][o] = v.w;
                int c = f >> 4, p4 = f & 15;
                *(f4*)&Bs[nb][c][p4 * 4] = j ? bv[1] : bv[0];
            }
        }
        __syncthreads();
    }

    #pragma unroll
    for (int ii = 0; ii < 4; ++ii) {
        int o = m0 + tm * 4 + ii;
        float bvs = bias[o];
        f4 v = { acc[ii][0] + bvs, acc[ii][1] + bvs, acc[ii][2] + bvs, acc[ii][3] + bvs };
        *(f4*)&E[(size_t)o * 4096 + n0 + tn * 4] = v;
    }
}

// ---------------------------------------------------------------------------
// aff_partial: part[seg][b][k][h][w] = sum_{c in seg's 64} Eg[c,h,w]*Ef[c,hc,wc]
// grid (64 h, 2 b, 4 seg), block 256 = (64 w) x (4 c-sub of 16 ch each).
// Global reads via wave-uniform SGPR base + fixed voffset regs; one barrier.
// ---------------------------------------------------------------------------
__global__ __launch_bounds__(256) void aff_partial(
    const float* __restrict__ Ef, const float* __restrict__ Eg,
    float* __restrict__ part)
{
    constexpr int DX[33] = DX_TBL;
    constexpr int DY[33] = DY_TBL;
    __shared__ float Laff[4][33][64];

    const int h = blockIdx.x, b = blockIdx.y, seg = blockIdx.z;
    const int tid = threadIdx.x;
    const int w = tid & 63, cs = tid >> 6;
    const size_t plane = (size_t)b * 256 * 4096;
    const float* EfB = Ef + plane;
    const float* EgB = Eg + plane;

    int voff[33];
    #pragma unroll
    for (int k = 0; k < 33; ++k) {
        int hc = iclamp(h + DX[k], 0, 63);
        int wc = iclamp(w + DY[k], 0, 63);
        voff[k] = hc * 64 + wc;
    }
    const int egoff = h * 64 + w;

    float aff[33];
    #pragma unroll
    for (int k = 0; k < 33; ++k) aff[k] = 0.f;

    const int c0 = seg * 64 + cs * 16;
    #pragma unroll 2
    for (int c = c0; c < c0 + 16; ++c) {
        const int cu = __builtin_amdgcn_readfirstlane(c);  // wave-uniform channel
        const float* base = EfB + cu * 4096;
        float eg = EgB[cu * 4096 + egoff];
        #pragma unroll
        for (int k = 0; k < 33; ++k)
            aff[k] += eg * base[voff[k]];
    }

    #pragma unroll
    for (int k = 0; k < 33; ++k) Laff[cs][k][w] = aff[k];
    __syncthreads();

    for (int idx = tid; idx < 33 * 64; idx += 256) {
        int k = idx >> 6, ww = idx & 63;
        float s = Laff[0][k][ww] + Laff[1][k][ww] + Laff[2][k][ww] + Laff[3][k][ww];
        part[(((size_t)seg * 2 + b) * 33 + k) * 4096 + h * 64 + ww] = s;
    }
}

// ---------------------------------------------------------------------------
// out_kernel: per-pixel softmax over 33 (summing the 4 c-seg partials, masking
// invalid offsets to -inf), then out[c] = sum_k wgt[k]*Ft[c,hc,wc].
// grid (64 h, 2 b, 4 c-quarters), block 256 = (64 w) x (4 c-sub).
// Softmax recomputed per thread in registers -> zero barriers, zero LDS.
// ---------------------------------------------------------------------------
__global__ __launch_bounds__(256) void out_kernel(
    const float* __restrict__ part, const float* __restrict__ Ft,
    float* __restrict__ out)
{
    constexpr int DX[33] = DX_TBL;
    constexpr int DY[33] = DY_TBL;

    const int h = blockIdx.x, b = blockIdx.y, cq = blockIdx.z;
    const int tid = threadIdx.x;
    const int w = tid & 63, cs = tid >> 6;

    float wgt[33];
    float m = -INFINITY;
    #pragma unroll
    for (int k = 0; k < 33; ++k) {
        float a = part[(((size_t)0 * 2 + b) * 33 + k) * 4096 + h * 64 + w]
                + part[(((size_t)1 * 2 + b) * 33 + k) * 4096 + h * 64 + w]
                + part[(((size_t)2 * 2 + b) * 33 + k) * 4096 + h * 64 + w]
                + part[(((size_t)3 * 2 + b) * 33 + k) * 4096 + h * 64 + w];
        bool valid = ((unsigned)(h + DX[k]) < 64u) && ((unsigned)(w + DY[k]) < 64u);
        a = valid ? a : -INFINITY;
        wgt[k] = a;
        m = fmaxf(m, a);
    }
    float ssum = 0.f;
    #pragma unroll
    for (int k = 0; k < 33; ++k) { float e = __expf(wgt[k] - m); wgt[k] = e; ssum += e; }
    float inv = 1.0f / ssum;
    #pragma unroll
    for (int k = 0; k < 33; ++k) wgt[k] *= inv;

    int voff[33];
    #pragma unroll
    for (int k = 0; k < 33; ++k) {
        int hc = iclamp(h + DX[k], 0, 63);
        int wc = iclamp(w + DY[k], 0, 63);
        voff[k] = hc * 64 + wc;
    }

    const size_t plane = (size_t)b * 256 * 4096;
    const float* FtB = Ft + plane;
    float* outB = out + plane;
    const int c0 = cq * 64 + cs * 16;
    #pragma unroll 2
    for (int c = c0; c < c0 + 16; ++c) {
        const int cu = __builtin_amdgcn_readfirstlane(c);
        const float* basep = FtB + cu * 4096;
        float acc = 0.f;
        #pragma unroll
        for (int k = 0; k < 33; ++k)
            acc += wgt[k] * basep[voff[k]];
        outB[cu * 4096 + h * 64 + w] = acc;
    }
}

// ---------------------------------------------------------------------------
extern "C" void kernel_launch(void* const* d_in, const int* in_sizes, int n_in,
                              void* d_out, int out_size, void* d_ws, size_t ws_size,
                              hipStream_t stream) {
    const float* Ft  = (const float*)d_in[0];
    const float* FtE = (const float*)d_in[1];
    const float* Wf  = (const float*)d_in[2];
    const float* bf  = (const float*)d_in[3];
    const float* Wg  = (const float*)d_in[4];
    const float* bg  = (const float*)d_in[5];
    float* out = (float*)d_out;

    // ws: Ef 8MB | Eg 8MB | part 4.3MB  (fp32)
    float* Ef = (float*)d_ws;
    float* Eg = Ef + (size_t)2 * 256 * 4096;
    float* part = Eg + (size_t)2 * 256 * 4096;   // [4 seg][2 b][33][4096]

    hipLaunchKernelGGL(gemm_f32, dim3(64, 4, 4), dim3(256), 0, stream,
                       Wf, bf, Wg, bg, Ft, FtE, Ef, Eg);
    hipLaunchKernelGGL(aff_partial, dim3(64, 2, 4), dim3(256), 0, stream,
                       Ef, Eg, part);
    hipLaunchKernelGGL(out_kernel, dim3(64, 2, 4), dim3(256), 0, stream,
                       part, Ft, out);
}

// Round 5
// 162.192 us; speedup vs baseline: 1.3462x; 1.3462x over previous
//
#include <hip/hip_runtime.h>
#include <math.h>

// B=2, C=O=256, H=W=64, K=33 offsets (D=4 rings).
typedef __attribute__((ext_vector_type(4))) float f4;

__device__ __forceinline__ int iclamp(int x, int lo, int hi) { return min(max(x, lo), hi); }

// k=0:(0,0); rings s=1..4: (-s,-s),(-s,0),(-s,s),(0,-s),(0,s),(s,-s),(s,0),(s,s)
#define DX_TBL {0, -1,-1,-1,0,0,1,1,1, -2,-2,-2,0,0,2,2,2, -3,-3,-3,0,0,3,3,3, -4,-4,-4,0,0,4,4,4}
#define DY_TBL {0, -1,0,1,-1,1,-1,0,1, -2,0,2,-2,2,-2,0,2, -3,0,3,-3,3,-3,0,3, -4,0,4,-4,4,-4,0,4}

// ---------------------------------------------------------------------------
// GEMM: E[b][o][p] = sum_c W[o][c] * X[b][c][p] + bias[o]
// M=256(o), N=4096(p), K=256(c). Tile 64o x 64p, K-chunk 32, reg double-buffer,
// one barrier per chunk. (256,4): 128-VGPR cap (needs ~70, no spill),
// 34KB LDS -> 4 blocks/CU, grid 1024 -> 16 waves/CU.
// ---------------------------------------------------------------------------
__global__ __launch_bounds__(256, 4) void gemm_f32(
    const float* __restrict__ Wf, const float* __restrict__ bf,
    const float* __restrict__ Wg, const float* __restrict__ bg,
    const float* __restrict__ Ft, const float* __restrict__ FtE,
    float* __restrict__ Ef, float* __restrict__ Eg)
{
    __shared__ float As[2][32][68];   // [c][o] transposed
    __shared__ float Bs[2][32][64];   // [c][p]

    const int bn = blockIdx.x, bm = blockIdx.y, gb = blockIdx.z;
    const int g = gb >> 1, b = gb & 1;
    const float* Wmat = g ? Wg : Wf;
    const float* bias = g ? bg : bf;
    const float* X = (g ? FtE : Ft) + (size_t)b * 256 * 4096;
    float* E = (g ? Eg : Ef) + (size_t)b * 256 * 4096;

    const int tid = threadIdx.x;
    const int tn = tid & 15, tm = tid >> 4;
    const int m0 = bm * 64, n0 = bn * 64;
    const int fa0 = tid, fa1 = tid + 256;

    float acc[4][4] = {};
    f4 av[2], bv[2];

    {
        av[0] = *(const f4*)&Wmat[(m0 + (fa0 >> 3)) * 256 + (fa0 & 7) * 4];
        av[1] = *(const f4*)&Wmat[(m0 + (fa1 >> 3)) * 256 + (fa1 & 7) * 4];
        bv[0] = *(const f4*)&X[((fa0 >> 4)) * 4096 + n0 + (fa0 & 15) * 4];
        bv[1] = *(const f4*)&X[((fa1 >> 4)) * 4096 + n0 + (fa1 & 15) * 4];
        #pragma unroll
        for (int j = 0; j < 2; ++j) {
            int f = j ? fa1 : fa0;
            int o = f >> 3, cq = f & 7;
            f4 v = j ? av[1] : av[0];
            As[0][cq * 4 + 0][o] = v.x; As[0][cq * 4 + 1][o] = v.y;
            As[0][cq * 4 + 2][o] = v.z; As[0][cq * 4 + 3][o] = v.w;
            int c = f >> 4, p4 = f & 15;
            *(f4*)&Bs[0][c][p4 * 4] = j ? bv[1] : bv[0];
        }
    }
    __syncthreads();

    for (int ch = 0; ch < 8; ++ch) {
        const int buf = ch & 1;
        if (ch < 7) {
            const int kk = (ch + 1) * 32;
            av[0] = *(const f4*)&Wmat[(m0 + (fa0 >> 3)) * 256 + kk + (fa0 & 7) * 4];
            av[1] = *(const f4*)&Wmat[(m0 + (fa1 >> 3)) * 256 + kk + (fa1 & 7) * 4];
            bv[0] = *(const f4*)&X[(kk + (fa0 >> 4)) * 4096 + n0 + (fa0 & 15) * 4];
            bv[1] = *(const f4*)&X[(kk + (fa1 >> 4)) * 4096 + n0 + (fa1 & 15) * 4];
        }
        #pragma unroll 8
        for (int k = 0; k < 32; ++k) {
            f4 a = *(const f4*)&As[buf][k][tm * 4];
            f4 bb = *(const f4*)&Bs[buf][k][tn * 4];
            #pragma unroll
            for (int ii = 0; ii < 4; ++ii)
                #pragma unroll
                for (int jj = 0; jj < 4; ++jj)
                    acc[ii][jj] += a[ii] * bb[jj];
        }
        if (ch < 7) {
            const int nb = buf ^ 1;
            #pragma unroll
            for (int j = 0; j < 2; ++j) {
                int f = j ? fa1 : fa0;
                int o = f >> 3, cq = f & 7;
                f4 v = j ? av[1] : av[0];
                As[nb][cq * 4 + 0][o] = v.x; As[nb][cq * 4 + 1][o] = v.y;
                As[nb][cq * 4 + 2][o] = v.z; As[nb][cq * 4 + 3][o] = v.w;
                int c = f >> 4, p4 = f & 15;
                *(f4*)&Bs[nb][c][p4 * 4] = j ? bv[1] : bv[0];
            }
        }
        __syncthreads();
    }

    #pragma unroll
    for (int ii = 0; ii < 4; ++ii) {
        int o = m0 + tm * 4 + ii;
        float bvs = bias[o];
        f4 v = { acc[ii][0] + bvs, acc[ii][1] + bvs, acc[ii][2] + bvs, acc[ii][3] + bvs };
        *(f4*)&E[(size_t)o * 4096 + n0 + tn * 4] = v;
    }
}

// ---------------------------------------------------------------------------
// wgt_kernel: full aff (256 channels) + softmax, writes normalized weights
// wgt[b][k][p].  grid (4 wt, 64 h, 2 b) = 512 blocks, block 256 = 16 w x 16 cs
// (16 channels each).  (256,2): 256-VGPR budget -> no spill (needs ~100).
// NOTE: cs = tid>>4 is NOT wave-uniform here -> plain per-lane c (no
// readfirstlane; that was R4's correctness bug).
// ---------------------------------------------------------------------------
__global__ __launch_bounds__(256, 2) void wgt_kernel(
    const float* __restrict__ Ef, const float* __restrict__ Eg,
    float* __restrict__ wgt)
{
    constexpr int DX[33] = DX_TBL;
    constexpr int DY[33] = DY_TBL;
    __shared__ float Laff[16][33][17];   // [cs][k][w16] padded
    __shared__ float Saff[33][16];

    const int wt = blockIdx.x, h = blockIdx.y, b = blockIdx.z;
    const int w0 = wt * 16;
    const int tid = threadIdx.x;
    const int w16 = tid & 15, cs = tid >> 4;
    const int w = w0 + w16;
    const size_t plane = (size_t)b * 256 * 4096;
    const float* EfB = Ef + plane;
    const float* EgB = Eg + plane;

    int voff[33];
    #pragma unroll
    for (int k = 0; k < 33; ++k) {
        int hc = iclamp(h + DX[k], 0, 63);
        int wc = iclamp(w + DY[k], 0, 63);
        voff[k] = hc * 64 + wc;
    }
    const int egoff = h * 64 + w;

    float aff[33];
    #pragma unroll
    for (int k = 0; k < 33; ++k) aff[k] = 0.f;

    const int c0 = cs * 16;
    #pragma unroll 2
    for (int c = c0; c < c0 + 16; ++c) {
        const float* base = EfB + c * 4096;           // per-lane base (cs varies within wave)
        float eg = EgB[c * 4096 + egoff];
        #pragma unroll
        for (int k = 0; k < 33; ++k)
            aff[k] += eg * base[voff[k]];
    }

    #pragma unroll
    for (int k = 0; k < 33; ++k) Laff[cs][k][w16] = aff[k];
    __syncthreads();

    // 16-way reduce over cs: 528 (k,w) slots
    for (int idx = tid; idx < 33 * 16; idx += 256) {
        int k = idx >> 4, ww = idx & 15;
        float s = 0.f;
        #pragma unroll
        for (int c = 0; c < 16; ++c) s += Laff[c][k][ww];
        Saff[k][ww] = s;
    }
    __syncthreads();

    // softmax per pixel (16 threads)
    if (tid < 16) {
        float v[33];
        float m = -INFINITY;
        #pragma unroll
        for (int k = 0; k < 33; ++k) {
            bool valid = ((unsigned)(h + DX[k]) < 64u) && ((unsigned)(w0 + tid + DY[k]) < 64u);
            float a = valid ? Saff[k][tid] : -INFINITY;
            v[k] = a;
            m = fmaxf(m, a);
        }
        float ssum = 0.f;
        #pragma unroll
        for (int k = 0; k < 33; ++k) { float e = __expf(v[k] - m); v[k] = e; ssum += e; }
        float inv = 1.0f / ssum;
        #pragma unroll
        for (int k = 0; k < 33; ++k) Saff[k][tid] = v[k] * inv;
    }
    __syncthreads();

    float* wgtB = wgt + (size_t)b * 33 * 4096;
    for (int idx = tid; idx < 33 * 16; idx += 256) {
        int k = idx >> 4, ww = idx & 15;
        wgtB[(size_t)k * 4096 + h * 64 + w0 + ww] = Saff[k][ww];
    }
}

// ---------------------------------------------------------------------------
// out_kernel: out[c][p] = sum_k wgt[k][p] * Ft[c][p+off_k].
// grid (64 h, 2 b, 8 cq) = 1024 blocks, block 256 = 64 w x 4 cs (8 ch each).
// cs = tid>>6 IS wave-uniform -> readfirstlane legal.
// (256,4): 128-VGPR cap (needs ~100: wv[33]+voff[33]), 16 waves/CU.
// ---------------------------------------------------------------------------
__global__ __launch_bounds__(256, 4) void out_kernel(
    const float* __restrict__ wgt, const float* __restrict__ Ft,
    float* __restrict__ out)
{
    constexpr int DX[33] = DX_TBL;
    constexpr int DY[33] = DY_TBL;

    const int h = blockIdx.x, b = blockIdx.y, cq = blockIdx.z;
    const int tid = threadIdx.x;
    const int w = tid & 63, cs = tid >> 6;
    const int p = h * 64 + w;

    const float* wgtB = wgt + (size_t)b * 33 * 4096;
    float wv[33];
    #pragma unroll
    for (int k = 0; k < 33; ++k) wv[k] = wgtB[(size_t)k * 4096 + p];

    int voff[33];
    #pragma unroll
    for (int k = 0; k < 33; ++k) {
        int hc = iclamp(h + DX[k], 0, 63);
        int wc = iclamp(w + DY[k], 0, 63);
        voff[k] = hc * 64 + wc;
    }

    const size_t plane = (size_t)b * 256 * 4096;
    const float* FtB = Ft + plane;
    float* outB = out + plane;
    const int c0 = cq * 32 + cs * 8;
    #pragma unroll 2
    for (int c = c0; c < c0 + 8; ++c) {
        const int cu = __builtin_amdgcn_readfirstlane(c);   // cs wave-uniform here
        const float* basep = FtB + cu * 4096;
        float acc = 0.f;
        #pragma unroll
        for (int k = 0; k < 33; ++k)
            acc += wv[k] * basep[voff[k]];
        outB[cu * 4096 + p] = acc;
    }
}

// ---------------------------------------------------------------------------
extern "C" void kernel_launch(void* const* d_in, const int* in_sizes, int n_in,
                              void* d_out, int out_size, void* d_ws, size_t ws_size,
                              hipStream_t stream) {
    const float* Ft  = (const float*)d_in[0];
    const float* FtE = (const float*)d_in[1];
    const float* Wf  = (const float*)d_in[2];
    const float* bf  = (const float*)d_in[3];
    const float* Wg  = (const float*)d_in[4];
    const float* bg  = (const float*)d_in[5];
    float* out = (float*)d_out;

    // ws: Ef 8.4MB | Eg 8.4MB | wgt 1.1MB  (fp32)
    float* Ef = (float*)d_ws;
    float* Eg = Ef + (size_t)2 * 256 * 4096;
    float* wgt = Eg + (size_t)2 * 256 * 4096;    // [2 b][33 k][4096 p]

    hipLaunchKernelGGL(gemm_f32, dim3(64, 4, 4), dim3(256), 0, stream,
                       Wf, bf, Wg, bg, Ft, FtE, Ef, Eg);
    hipLaunchKernelGGL(wgt_kernel, dim3(4, 64, 2), dim3(256), 0, stream,
                       Ef, Eg, wgt);
    hipLaunchKernelGGL(out_kernel, dim3(64, 2, 8), dim3(256), 0, stream,
                       wgt, Ft, out);
}

// Round 6
// 141.389 us; speedup vs baseline: 1.5443x; 1.1471x over previous
//
#include <hip/hip_runtime.h>
#include <math.h>

// B=2, C=O=256, H=W=64, K=33 offsets (D=4 rings).
typedef __attribute__((ext_vector_type(4))) float f4;

__device__ __forceinline__ int iclamp(int x, int lo, int hi) { return min(max(x, lo), hi); }

// k=0:(0,0); rings s=1..4: (-s,-s),(-s,0),(-s,s),(0,-s),(0,s),(s,-s),(s,0),(s,s)
__device__ constexpr int DXC[33] = {0, -1,-1,-1,0,0,1,1,1, -2,-2,-2,0,0,2,2,2, -3,-3,-3,0,0,3,3,3, -4,-4,-4,0,0,4,4,4};
__device__ constexpr int DYC[33] = {0, -1,0,1,-1,1,-1,0,1, -2,0,2,-2,2,-2,0,2, -3,0,3,-3,3,-3,0,3, -4,0,4,-4,4,-4,0,4};

// ---------------------------------------------------------------------------
// GEMM v2: E[b][o][p] = sum_c W[o][c]*X[b][c][p] + bias[o]
// 128(o) x 64(p) tile, 8x4 acc/thread. Per k: 3 ds_read_b128 (broadcast-heavy)
// per 32 FMA-inst -> VALU-bound. Grid (64 nt, 2 mt, 4 gb) = 512 blocks,
// LDS 50 KB dbuf -> 2 blocks/CU (grid-limited anyway), 8 waves/CU.
// ---------------------------------------------------------------------------
__global__ __launch_bounds__(256, 2) void gemm_f32(
    const float* __restrict__ Wf, const float* __restrict__ bf,
    const float* __restrict__ Wg, const float* __restrict__ bg,
    const float* __restrict__ Ft, const float* __restrict__ FtE,
    float* __restrict__ Ef, float* __restrict__ Eg)
{
    __shared__ float As[2][32][132];   // [c][o] transposed, pad 132 (4-way on stores only)
    __shared__ float Bs[2][32][64];    // [c][p]

    const int bn = blockIdx.x, bm = blockIdx.y, gb = blockIdx.z;
    const int g = gb >> 1, b = gb & 1;
    const float* Wmat = g ? Wg : Wf;
    const float* bias = g ? bg : bf;
    const float* X = (g ? FtE : Ft) + (size_t)b * 256 * 4096;
    float* E = (g ? Eg : Ef) + (size_t)b * 256 * 4096;

    const int tid = threadIdx.x;
    const int tn = tid & 15, tm = tid >> 4;
    const int m0 = bm * 128, n0 = bn * 64;

    float acc[8][4] = {};
    f4 areg[4], breg[2];

    auto loadA = [&](int kk) {
        #pragma unroll
        for (int i = 0; i < 4; ++i) {
            int f = i * 256 + tid, m = f >> 3, cq = f & 7;
            areg[i] = *(const f4*)&Wmat[(m0 + m) * 256 + kk + cq * 4];
        }
    };
    auto loadB = [&](int kk) {
        #pragma unroll
        for (int i = 0; i < 2; ++i) {
            int f = i * 256 + tid, c = f >> 4, n4 = f & 15;
            breg[i] = *(const f4*)&X[(size_t)(kk + c) * 4096 + n0 + n4 * 4];
        }
    };
    auto storeLDS = [&](int buf) {
        #pragma unroll
        for (int i = 0; i < 4; ++i) {
            int f = i * 256 + tid, m = f >> 3, cq = f & 7;
            As[buf][cq * 4 + 0][m] = areg[i].x;
            As[buf][cq * 4 + 1][m] = areg[i].y;
            As[buf][cq * 4 + 2][m] = areg[i].z;
            As[buf][cq * 4 + 3][m] = areg[i].w;
        }
        #pragma unroll
        for (int i = 0; i < 2; ++i) {
            int f = i * 256 + tid, c = f >> 4, n4 = f & 15;
            *(f4*)&Bs[buf][c][n4 * 4] = breg[i];
        }
    };

    loadA(0); loadB(0); storeLDS(0);
    __syncthreads();

    for (int ch = 0; ch < 8; ++ch) {
        const int buf = ch & 1;
        if (ch < 7) { loadA((ch + 1) * 32); loadB((ch + 1) * 32); }
        #pragma unroll 4
        for (int k = 0; k < 32; ++k) {
            f4 a0 = *(const f4*)&As[buf][k][tm * 8];
            f4 a1 = *(const f4*)&As[buf][k][tm * 8 + 4];
            f4 bb = *(const f4*)&Bs[buf][k][tn * 4];
            #pragma unroll
            for (int ii = 0; ii < 4; ++ii)
                #pragma unroll
                for (int jj = 0; jj < 4; ++jj) {
                    acc[ii][jj]     += a0[ii] * bb[jj];
                    acc[4 + ii][jj] += a1[ii] * bb[jj];
                }
        }
        if (ch < 7) storeLDS(buf ^ 1);
        __syncthreads();
    }

    #pragma unroll
    for (int r = 0; r < 8; ++r) {
        int o = m0 + tm * 8 + r;
        float bvs = bias[o];
        f4 v = { acc[r][0] + bvs, acc[r][1] + bvs, acc[r][2] + bvs, acc[r][3] + bvs };
        *(f4*)&E[(size_t)o * 4096 + n0 + tn * 4] = v;
    }
}

// ---------------------------------------------------------------------------
// aff_part: part[cseg][b][k][p] = sum_{c in cseg's 64} Eg[c,p]*Ef[c,p+off_k]
// grid (64 h, 2 b, 4 cseg) = 512 blocks, block 256 = 64 w x 4 k-groups
// (contiguous k ranges -> ds_read2-pairable imm offsets).
// LDS: double-buffered [10 rows (9 Ef h-halo + 1 Eg)][8 ch][72 w-halo],
// w-halo PRE-CLAMPED at staging -> compute is pure base+imm ds_read.
// ---------------------------------------------------------------------------
template<int K0, int NK>
__device__ __forceinline__ void aff_accum(const float* __restrict__ base, float* __restrict__ aff)
{
    #pragma unroll
    for (int ch = 0; ch < 8; ++ch) {
        float eg = base[(72 + ch) * 72];          // d=9 row
        #pragma unroll
        for (int j = 0; j < NK; ++j) {
            constexpr int kk0 = K0;               // force compile-time
            int k = kk0 + j;
            aff[j] += eg * base[((DXC[k] + 4) * 8 + ch) * 72 + DYC[k]];
        }
    }
}

__global__ __launch_bounds__(256, 2) void aff_part(
    const float* __restrict__ Ef, const float* __restrict__ Eg,
    float* __restrict__ part)
{
    __shared__ float L[2][10 * 8 * 72];   // [d][ch][72]

    const int h = blockIdx.x, b = blockIdx.y, cseg = blockIdx.z;
    const int tid = threadIdx.x;
    const int w = tid & 63, kg = tid >> 6;    // kg wave-uniform
    const size_t plane = (size_t)b * 256 * 4096;
    const float* EfB = Ef + plane;
    const float* EgB = Eg + plane;
    const int cbase = cseg * 64;

    int hr[10];
    #pragma unroll
    for (int d = 0; d < 10; ++d) hr[d] = (d < 9) ? iclamp(h + d - 4, 0, 63) : h;

    f4 vreg[5]; float sreg[3];

    auto load_rnd = [&](int r) {
        const int c0 = cbase + r * 8;
        #pragma unroll
        for (int i = 0; i < 5; ++i) {
            int f = i * 256 + tid, d = f >> 7, rem = f & 127, ch = rem >> 4, c4 = rem & 15;
            const float* src = (d < 9) ? EfB : EgB;
            vreg[i] = *(const f4*)&src[(size_t)(c0 + ch) * 4096 + hr[d] * 64 + c4 * 4];
        }
        #pragma unroll
        for (int i = 0; i < 3; ++i) {
            int e = i * 256 + tid;
            if (e < 640) {
                int row = e >> 3, sc = e & 7, d = row >> 3, ch = row & 7;
                int wsrc = (sc < 4) ? 0 : 63;
                const float* src = (d < 9) ? EfB : EgB;
                sreg[i] = src[(size_t)(c0 + ch) * 4096 + hr[d] * 64 + wsrc];
            }
        }
    };
    auto store_rnd = [&](int buf) {
        float* Lb = L[buf];
        #pragma unroll
        for (int i = 0; i < 5; ++i) {
            int f = i * 256 + tid, d = f >> 7, rem = f & 127, ch = rem >> 4, c4 = rem & 15;
            *(f4*)&Lb[(d * 8 + ch) * 72 + 4 + c4 * 4] = vreg[i];
        }
        #pragma unroll
        for (int i = 0; i < 3; ++i) {
            int e = i * 256 + tid;
            if (e < 640) {
                int row = e >> 3, sc = e & 7, d = row >> 3, ch = row & 7;
                int col = (sc < 4) ? sc : (64 + sc);
                Lb[(d * 8 + ch) * 72 + col] = sreg[i];
            }
        }
    };

    float aff[9] = {0.f,0.f,0.f,0.f,0.f,0.f,0.f,0.f,0.f};

    load_rnd(0); store_rnd(0);
    for (int r = 0; r < 8; ++r) {
        if (r < 7) load_rnd(r + 1);
        __syncthreads();
        const float* base = &L[r & 1][4 + w];
        switch (kg) {                      // wave-uniform branch
            case 0: aff_accum<0, 9>(base, aff); break;
            case 1: aff_accum<9, 8>(base, aff); break;
            case 2: aff_accum<17, 8>(base, aff); break;
            default: aff_accum<25, 8>(base, aff); break;
        }
        if (r < 7) store_rnd((r + 1) & 1);
    }

    const int k0 = (kg == 0) ? 0 : (kg == 1) ? 9 : (kg == 2) ? 17 : 25;
    const int nk = (kg == 0) ? 9 : 8;
    float* pB = part + (((size_t)cseg * 2 + b) * 33) * 4096 + h * 64 + w;
    for (int j = 0; j < nk; ++j) pB[(size_t)(k0 + j) * 4096] = aff[j];
}

// ---------------------------------------------------------------------------
// softmax_k: per pixel sum 4 partials, mask invalid -> -inf, softmax, write
// wgt[b][k][p]. 8192 threads (32 blocks).
// ---------------------------------------------------------------------------
__global__ __launch_bounds__(256, 2) void softmax_k(
    const float* __restrict__ part, float* __restrict__ wgt)
{
    const int id = blockIdx.x * 256 + threadIdx.x;
    const int b = id >> 12, p = id & 4095;
    const int h = p >> 6, w = p & 63;

    float a[33];
    float m = -INFINITY;
    #pragma unroll
    for (int k = 0; k < 33; ++k) {
        float s = part[(((size_t)0 * 2 + b) * 33 + k) * 4096 + p]
                + part[(((size_t)1 * 2 + b) * 33 + k) * 4096 + p]
                + part[(((size_t)2 * 2 + b) * 33 + k) * 4096 + p]
                + part[(((size_t)3 * 2 + b) * 33 + k) * 4096 + p];
        bool valid = ((unsigned)(h + DXC[k]) < 64u) && ((unsigned)(w + DYC[k]) < 64u);
        a[k] = valid ? s : -INFINITY;
        m = fmaxf(m, a[k]);
    }
    float ssum = 0.f;
    #pragma unroll
    for (int k = 0; k < 33; ++k) { float e = __expf(a[k] - m); a[k] = e; ssum += e; }
    float inv = 1.0f / ssum;
    float* wgtB = wgt + (size_t)b * 33 * 4096 + p;
    #pragma unroll
    for (int k = 0; k < 33; ++k) wgtB[(size_t)k * 4096] = a[k] * inv;
}

// ---------------------------------------------------------------------------
// out v2: out[c][p] = sum_k wgt[k,p]*Ft[c,p+off_k].  Same staging skeleton as
// aff_part (9 Ft h-halo rows, w-halo pre-clamped). grid (64 h, 2 b, 4 cseg),
// block 256 = 64 w x 4 cg (2 ch each per 8-ch round). wv[33] in regs.
// Invalid k has wgt==0 -> clamped gather contributes 0.
// ---------------------------------------------------------------------------
__global__ __launch_bounds__(256, 2) void out_kernel(
    const float* __restrict__ wgt, const float* __restrict__ Ft,
    float* __restrict__ out)
{
    __shared__ float L[2][9 * 8 * 72];

    const int h = blockIdx.x, b = blockIdx.y, cseg = blockIdx.z;
    const int tid = threadIdx.x;
    const int w = tid & 63, cg = tid >> 6;    // cg wave-uniform
    const size_t plane = (size_t)b * 256 * 4096;
    const float* FtB = Ft + plane;
    float* outB = out + plane;
    const int cbase = cseg * 64;
    const int p = h * 64 + w;

    const float* wgtB = wgt + (size_t)b * 33 * 4096 + p;
    float wv[33];
    #pragma unroll
    for (int k = 0; k < 33; ++k) wv[k] = wgtB[(size_t)k * 4096];

    int hr[9];
    #pragma unroll
    for (int d = 0; d < 9; ++d) hr[d] = iclamp(h + d - 4, 0, 63);

    f4 vreg[5]; float sreg[3];

    auto load_rnd = [&](int r) {
        const int c0 = cbase + r * 8;
        #pragma unroll
        for (int i = 0; i < 5; ++i) {
            int f = i * 256 + tid;
            if (f < 1152) {
                int d = f >> 7, rem = f & 127, ch = rem >> 4, c4 = rem & 15;
                vreg[i] = *(const f4*)&FtB[(size_t)(c0 + ch) * 4096 + hr[d] * 64 + c4 * 4];
            }
        }
        #pragma unroll
        for (int i = 0; i < 3; ++i) {
            int e = i * 256 + tid;
            if (e < 576) {
                int row = e >> 3, sc = e & 7, d = row >> 3, ch = row & 7;
                int wsrc = (sc < 4) ? 0 : 63;
                sreg[i] = FtB[(size_t)(c0 + ch) * 4096 + hr[d] * 64 + wsrc];
            }
        }
    };
    auto store_rnd = [&](int buf) {
        float* Lb = L[buf];
        #pragma unroll
        for (int i = 0; i < 5; ++i) {
            int f = i * 256 + tid;
            if (f < 1152) {
                int d = f >> 7, rem = f & 127, ch = rem >> 4, c4 = rem & 15;
                *(f4*)&Lb[(d * 8 + ch) * 72 + 4 + c4 * 4] = vreg[i];
            }
        }
        #pragma unroll
        for (int i = 0; i < 3; ++i) {
            int e = i * 256 + tid;
            if (e < 576) {
                int row = e >> 3, sc = e & 7, d = row >> 3, ch = row & 7;
                int col = (sc < 4) ? sc : (64 + sc);
                Lb[(d * 8 + ch) * 72 + col] = sreg[i];
            }
        }
    };

    load_rnd(0); store_rnd(0);
    for (int r = 0; r < 8; ++r) {
        if (r < 7) load_rnd(r + 1);
        __syncthreads();
        const float* base = &L[r & 1][4 + w];
        #pragma unroll
        for (int u = 0; u < 2; ++u) {
            const float* b2 = base + (cg * 2 + u) * 72;
            float o = 0.f;
            #pragma unroll
            for (int k = 0; k < 33; ++k)
                o += wv[k] * b2[(DXC[k] + 4) * 576 + DYC[k]];
            int c = cbase + r * 8 + cg * 2 + u;
            outB[(size_t)c * 4096 + p] = o;
        }
        if (r < 7) store_rnd((r + 1) & 1);
    }
}

// ---------------------------------------------------------------------------
extern "C" void kernel_launch(void* const* d_in, const int* in_sizes, int n_in,
                              void* d_out, int out_size, void* d_ws, size_t ws_size,
                              hipStream_t stream) {
    const float* Ft  = (const float*)d_in[0];
    const float* FtE = (const float*)d_in[1];
    const float* Wf  = (const float*)d_in[2];
    const float* bf  = (const float*)d_in[3];
    const float* Wg  = (const float*)d_in[4];
    const float* bg  = (const float*)d_in[5];
    float* out = (float*)d_out;

    // ws (~256 MB available): Ef 8.4MB | Eg 8.4MB | part 4.3MB | wgt 1.1MB
    float* Ef  = (float*)d_ws;
    float* Eg  = Ef + (size_t)2 * 256 * 4096;
    float* part = Eg + (size_t)2 * 256 * 4096;   // [4 cseg][2 b][33][4096]
    float* wgt = part + (size_t)4 * 2 * 33 * 4096; // [2 b][33][4096]

    hipLaunchKernelGGL(gemm_f32, dim3(64, 2, 4), dim3(256), 0, stream,
                       Wf, bf, Wg, bg, Ft, FtE, Ef, Eg);
    hipLaunchKernelGGL(aff_part, dim3(64, 2, 4), dim3(256), 0, stream,
                       Ef, Eg, part);
    hipLaunchKernelGGL(softmax_k, dim3(32), dim3(256), 0, stream,
                       part, wgt);
    hipLaunchKernelGGL(out_kernel, dim3(64, 2, 4), dim3(256), 0, stream,
                       wgt, Ft, out);
}